// Round 24
// baseline (33.289 us; speedup 1.0000x reference)
//
#include <hip/hip_runtime.h>

// ShiftGraph: B=8, C=16, H=W=256, d=5 (r=2), 24 shifts.
// Output (flat float32): edges (B, E, 2) then ws (B, E), E = 1557540.
// R22: SINGLE-BARRIER full-stage. 512-thr blocks (2 rows), stage all 16ch x
// 4 rows (64 KB, 2 blocks/CU, 1024 blocks -> 2 pipelined generations), one
// __syncthreads, centers cached in 16 VGPRs, then 12 shift-passes computing
// from LDS and storing IMMEDIATELY (stores spread across whole phase, waves
// fully async). Pair symmetry + own/mirror stores as R18.

#define HH 256
#define WW 256
#define CC 16
#define BB 8
#define HW (HH * WW)
#define EE 1557540

__global__ __launch_bounds__(512) void shiftgraph_kernel(
    const float* __restrict__ x, float* __restrict__ out) {
    __shared__ float lds[16384];     // [16ch][4rows][256cols] = 64 KB
    const int bid = blockIdx.x;      // 0..1023
    const int b  = bid & 7;          // batch -> XCD
    const int hg = bid >> 3;         // row-pair 0..127
    const int tid = threadIdx.x;     // 0..511
    const int rr = tid >> 8;         // 0/1, wave-uniform
    const int w  = tid & 255;
    const int h  = hg * 2 + rr;

    const float* __restrict__ xb = x + (size_t)b * (CC * HW);

    // ---- stage: 16ch x 4rows x 256cols, 8 float4 per thread ----
#pragma unroll
    for (int inst = 0; inst < 8; ++inst) {
        const int flatf = inst * 2048 + tid * 4;
        const int ch  = flatf >> 10;         // 1024 floats per channel
        const int rem = flatf & 1023;
        const int row = rem >> 8;
        const int col = rem & 255;
        int hr = hg * 2 + row; hr = hr > HH - 1 ? HH - 1 : hr;  // clamp: guarded
        *reinterpret_cast<float4*>(&lds[flatf]) =
            *reinterpret_cast<const float4*>(xb + ch * HW + hr * WW + col);
    }
    __syncthreads();                 // the ONLY barrier

    // center cache: 16 VGPRs
    float ctr[CC];
#pragma unroll
    for (int c = 0; c < CC; ++c) ctr[c] = lds[c * 1024 + rr * 256 + w];

    float* __restrict__ edges = out;                        // (B, E, 2)
    float* __restrict__ wsp   = out + (size_t)BB * EE * 2;  // (B, E)
    const size_t bE = (size_t)b * EE;
    const int posc = h * WW + w;

    // ---- 12 shift-passes: compute from LDS, store immediately ----
#pragma unroll
    for (int di = 0; di <= 2; ++di) {
#pragma unroll
        for (int dj = (di == 0 ? 1 : -2); dj <= 2; ++dj) {
            const int i = di + 2, j = dj + 2;
            if (h + di >= HH) continue;          // wave-uniform (rr uniform/wave)
            const int w2 = w + dj;
            const bool wok = (w2 >= 0 && w2 < WW);
            int wn = w + dj; wn = wn < 0 ? 0 : (wn > WW - 1 ? WW - 1 : wn);
            const int nbase = (rr + di) * 256 + wn;   // clamped: guarded lanes

            float acc = 0.0f;
#pragma unroll
            for (int c = 0; c < CC; ++c) {
                const float d = lds[c * 1024 + nbase] - ctr[c];
                acc = fmaf(d, d, acc);
            }

            if (wok) {
                const float scale = sqrtf((float)(di * di + dj * dj));
                const float wsv = -acc * scale;

                int offF = 0, offM = 0;          // compile-time prefixes
#pragma unroll
                for (int m = 0; m < 25; ++m) {
                    const int mi = m / 5, mj = m % 5;
                    if (mi == 2 && mj == 2) continue;
                    const int cm = (HH - (mi < 2 ? 2 - mi : mi - 2)) *
                                   (WW - (mj < 2 ? 2 - mj : mj - 2));
                    if (m < i * 5 + j) offF += cm;
                    if (m < (4 - i) * 5 + (4 - j)) offM += cm;
                }
                const int cww = WW - (dj < 0 ? -dj : dj);
                const int e1 = offF + h * cww + (w - (dj < 0 ? -dj : 0));
                const int e2 = offM + h * cww + (w + (dj < 0 ? dj : 0));
                const int posv = di * WW + dj;

                *reinterpret_cast<float2*>(edges + (bE + e1) * 2) =
                    make_float2((float)posc, (float)(posc + posv));
                *reinterpret_cast<float2*>(edges + (bE + e2) * 2) =
                    make_float2((float)(posc + posv), (float)posc);
                wsp[bE + e1] = wsv;
                wsp[bE + e2] = wsv;
            }
        }
    }
}

extern "C" void kernel_launch(void* const* d_in, const int* in_sizes, int n_in,
                              void* d_out, int out_size, void* d_ws, size_t ws_size,
                              hipStream_t stream) {
    const float* x = (const float*)d_in[0];
    float* out = (float*)d_out;
    dim3 block(512);           // 2 rows x 256 cols
    dim3 grid(128 * BB);       // one block per (row-pair, batch)
    shiftgraph_kernel<<<grid, block, 0, stream>>>(x, out);
}